// Round 8
// baseline (402.716 us; speedup 1.0000x reference)
//
#include <hip/hip_runtime.h>
#include <math.h>

#define NPG   200                 // nodes per graph
#define HDIM  128
#define NG    256
#define NT_T  (NG * NPG)          // 51200
#define EPG_  3200
#define E_T   (NG * EPG_)         // 819200
#define KP1   224                 // layer-1 K (200) padded to mult of 32
#define APITCH 224                // A' row pitch (zero cols >= 200)
#define XPAD  224                 // converted-X row pitch (zero cols >= 200)
#define TTP   232                 // Tt LDS pitch (shorts): 464B, 16B-aligned rows
#define W1SZ  (256 * KP1)
#define W2SZ  (256 * HDIM)

// prep-kernel grid partition
#define NB_ADJ (2 * NG)                       // 512
#define NB_CX  (2 * NT_T * 28 / 256)          // 11200
#define NB_CW  ((2 * (W1SZ + W2SZ)) / 256)    // 704
#define NB_PREP (NB_ADJ + NB_CX + NB_CW + 1)

typedef short short8 __attribute__((ext_vector_type(8)));
typedef float f32x4  __attribute__((ext_vector_type(4)));

__device__ __forceinline__ unsigned short f2bf(float f) {
    union { float f; unsigned int u; } v; v.f = f;
    unsigned int u = v.u;
    u += 0x7FFFu + ((u >> 16) & 1u);       // RNE
    return (unsigned short)(u >> 16);
}

// ---------------------------------------------------------------------------
// Union prep kernel: [0,512) adjacency build; [512,11712) X convert;
// [11712,12416) W convert; last block zeroes the per-graph MLP counters.
// ---------------------------------------------------------------------------
__global__ __launch_bounds__(256) void prep_kernel(
        const int* __restrict__ sc_ei, const int* __restrict__ fc_ei,
        const float* __restrict__ sc_x, const float* __restrict__ fc_x,
        const float* __restrict__ s1r, const float* __restrict__ s1o,
        const float* __restrict__ f1r, const float* __restrict__ f1o,
        const float* __restrict__ s2r, const float* __restrict__ s2o,
        const float* __restrict__ f2r, const float* __restrict__ f2o,
        unsigned short* __restrict__ A, unsigned short* __restrict__ xb,
        unsigned short* __restrict__ wb, int* __restrict__ gcnt) {
    const int b = blockIdx.x, t = threadIdx.x;

    if (b < NB_ADJ) {
        // ---- adjacency: A' = count/max(deg,1) bf16, [branch][g][dst][src pad 224]
        __shared__ unsigned int cnt[10000];    // 200*200 u8 counters in u32
        __shared__ float invdeg[200];
        const int branch = b >> 8, g = b & 255;
        const int* ei = branch ? fc_ei : sc_ei;

        for (int i = t; i < 10000; i += 256) cnt[i] = 0u;
        __syncthreads();
        const int ebase = g * EPG_;
        for (int i = t; i < EPG_; i += 256) {
            int src = ei[ebase + i];
            int dst = ei[E_T + ebase + i];
            int idx = (dst - g * NPG) * NPG + (src - g * NPG);
            atomicAdd(&cnt[idx >> 2], 1u << ((idx & 3) * 8));
        }
        __syncthreads();
        if (t < NPG) {
            unsigned int s = 0;
            for (int w = 0; w < 50; ++w) {
                unsigned int v = cnt[t * 50 + w];
                s += (v & 0xFFu) + ((v >> 8) & 0xFFu) + ((v >> 16) & 0xFFu) + ((v >> 24) & 0xFFu);
            }
            invdeg[t] = 1.0f / fmaxf((float)s, 1.0f);
        }
        __syncthreads();
        unsigned short* Ag = A + ((size_t)branch * NG + g) * NPG * APITCH;
        for (int q = t; q < NPG * (APITCH / 4); q += 256) {
            int row = q / 56;
            int c4  = (q - row * 56) * 4;
            float inv = invdeg[row];
            ushort4 o;
            unsigned short* po = (unsigned short*)&o;
#pragma unroll
            for (int j = 0; j < 4; ++j) {
                int col = c4 + j;
                float v = 0.0f;
                if (col < NPG) {
                    unsigned int w = cnt[row * 50 + (col >> 2)];
                    v = (float)((w >> ((col & 3) * 8)) & 0xFFu) * inv;
                }
                po[j] = f2bf(v);
            }
            *(ushort4*)&Ag[row * APITCH + c4] = o;
        }
    } else if (b < NB_ADJ + NB_CX) {
        // ---- X fp32 [NT,200] -> bf16 [NT,224]
        int c = (b - NB_ADJ) * 256 + t;
        int branch = c / (NT_T * 28);
        int rem = c - branch * (NT_T * 28);
        int node = rem / 28;
        int koff = (rem - node * 28) * 8;
        const float* x = branch ? fc_x : sc_x;
        uint4 o;
        if (koff < 200) {
            const float* p = x + (size_t)node * 200 + koff;
            float4 a = *(const float4*)p;
            float4 bb = *(const float4*)(p + 4);
            o.x = (unsigned)f2bf(a.x) | ((unsigned)f2bf(a.y) << 16);
            o.y = (unsigned)f2bf(a.z) | ((unsigned)f2bf(a.w) << 16);
            o.z = (unsigned)f2bf(bb.x) | ((unsigned)f2bf(bb.y) << 16);
            o.w = (unsigned)f2bf(bb.z) | ((unsigned)f2bf(bb.w) << 16);
        } else {
            o.x = o.y = o.z = o.w = 0u;
        }
        *(uint4*)&xb[((size_t)branch * NT_T + node) * XPAD + koff] = o;
    } else if (b < NB_ADJ + NB_CX + NB_CW) {
        // ---- weights -> packed W^T bf16 [br0L1|br1L1|br0L2|br1L2], rel|root rows
        int idx = (b - NB_ADJ - NB_CX) * 256 + t;
        float v = 0.0f;
        if (idx < 2 * W1SZ) {
            int branch = idx / W1SZ, rem = idx - branch * W1SZ;
            int c = rem / KP1, k = rem - c * KP1;
            const float* wr = branch ? f1r : s1r;
            const float* wo = branch ? f1o : s1o;
            if (k < 200) v = (c < 128) ? wr[(size_t)k * 128 + c] : wo[(size_t)k * 128 + (c - 128)];
        } else {
            int i2 = idx - 2 * W1SZ;
            int branch = i2 / W2SZ, rem = i2 - branch * W2SZ;
            int c = rem / HDIM, k = rem - c * HDIM;
            const float* wr = branch ? f2r : s2r;
            const float* wo = branch ? f2o : s2o;
            v = (c < 128) ? wr[(size_t)k * 128 + c] : wo[(size_t)k * 128 + (c - 128)];
        }
        wb[idx] = f2bf(v);
    } else {
        if (t < NG) gcnt[t] = 0;
    }
}

// ---------------------------------------------------------------------------
// Fused GraphConv layer (merged X-scan + agg + pool), launch_bounds(256,1):
// 512-reg V+A budget -> compiler can hoist loads deeply (1 block/CU, 4 waves).
// Phase C's A' loads (independent of Tt) are explicitly issued BEFORE the
// barrier (apre, 4 of 7 iters) to overlap the barrier drain with HBM fetch.
// For !IS_L1: the last of each graph's 4 blocks runs the MLP head + log_softmax
// (threadfence + device-scope atomic counter pattern).
// ---------------------------------------------------------------------------
template<bool IS_L1>
__global__ __launch_bounds__(256, 1) void layer_kernel(
        const unsigned short* __restrict__ Xb,     // L1 input, pitch 224
        const unsigned short* __restrict__ hin,    // L2 input, pitch 128
        const unsigned short* __restrict__ Wall,
        const unsigned short* __restrict__ Aall,
        const float* __restrict__ brel_sc, const float* __restrict__ brel_fc,
        unsigned short* __restrict__ Hout,
        float* __restrict__ z, int zlayer,
        int* __restrict__ gcnt,
        const float* __restrict__ w1, const float* __restrict__ b1,
        const float* __restrict__ w2, const float* __restrict__ b2,
        const float* __restrict__ w3, const float* __restrict__ b3,
        float* __restrict__ out) {
    __shared__ alignas(16) short Tt[64 * TTP];   // 29,696 B
    __shared__ float zsum[64];

    const int tid = threadIdx.x;
    const int lane = tid & 63, wid = tid >> 6;     // 4 waves
    const int l15 = lane & 15, quad = lane >> 4;
    const int half = blockIdx.x;                   // 0/1: channel half
    const int g = blockIdx.y, branch = blockIdx.z;

    if (tid < 64) zsum[tid] = 0.0f;

    const int KITER = IS_L1 ? 7 : 4;
    const int XP    = IS_L1 ? XPAD : HDIM;
    const int WP    = IS_L1 ? KP1 : HDIM;
    const unsigned short* X = (IS_L1 ? Xb : hin) + (size_t)branch * NT_T * XP;
    const unsigned short* W = Wall + (IS_L1 ? (size_t)branch * W1SZ
                                            : (size_t)2 * W1SZ + (size_t)branch * W2SZ);
    const unsigned short* Xg = X + (size_t)g * NPG * XP;
    const unsigned short* Ag = Aall + ((size_t)branch * NG + g) * NPG * APITCH;

    const int ms = wid & 1;        // node-tile set
    const int ns = wid >> 1;       // channel-tile set

    int nrow[7];
#pragma unroll
    for (int mt = 0; mt < 7; ++mt) {
        int s = (ms * 7 + mt) * 16 + l15;
        nrow[mt] = (s > NPG - 1) ? (NPG - 1) : s;   // clamp; killed by A'=0 / mask
    }
    int wrel_row[2];
#pragma unroll
    for (int nt = 0; nt < 2; ++nt)
        wrel_row[nt] = half * 64 + (ns * 2 + nt) * 16 + l15;

    f32x4 accT[7][2];   // D[m=s][n=c]
    f32x4 accH[2][7];   // D[m=c][n=d]
#pragma unroll
    for (int mt = 0; mt < 7; ++mt)
#pragma unroll
        for (int nt = 0; nt < 2; ++nt)
#pragma unroll
            for (int r = 0; r < 4; ++r) { accT[mt][nt][r] = 0.0f; accH[nt][mt][r] = 0.0f; }

    // ======== Merged X-scan: transform + root term in one pass ========
#pragma unroll
    for (int ki = 0; ki < KITER; ++ki) {
        const int kb = ki * 32 + quad * 8;
        short8 xf[7];
#pragma unroll
        for (int mt = 0; mt < 7; ++mt)
            xf[mt] = *(const short8*)&Xg[nrow[mt] * XP + kb];
        short8 wr[2], wo[2];
#pragma unroll
        for (int nt = 0; nt < 2; ++nt) {
            wr[nt] = *(const short8*)&W[(size_t)wrel_row[nt] * WP + kb];
            wo[nt] = *(const short8*)&W[(size_t)(128 + wrel_row[nt]) * WP + kb];
        }
#pragma unroll
        for (int mt = 0; mt < 7; ++mt)
#pragma unroll
            for (int nt = 0; nt < 2; ++nt)
                accT[mt][nt] = __builtin_amdgcn_mfma_f32_16x16x32_bf16(xf[mt], wr[nt], accT[mt][nt], 0, 0, 0);
#pragma unroll
        for (int nt = 0; nt < 2; ++nt)
#pragma unroll
            for (int mt = 0; mt < 7; ++mt)
                accH[nt][mt] = __builtin_amdgcn_mfma_f32_16x16x32_bf16(wo[nt], xf[mt], accH[nt][mt], 0, 0, 0);
    }

    // accT -> Tt (lane holds s = quad*4+r, c = l15)
#pragma unroll
    for (int mt = 0; mt < 7; ++mt) {
        int s0 = (ms * 7 + mt) * 16 + quad * 4;
#pragma unroll
        for (int nt = 0; nt < 2; ++nt) {
            int c = (ns * 2 + nt) * 16 + l15;
            ushort4 o;
            unsigned short* po = (unsigned short*)&o;
#pragma unroll
            for (int r = 0; r < 4; ++r) po[r] = f2bf(accT[mt][nt][r]);
            *(ushort4*)&Tt[c * TTP + s0] = o;
        }
    }

    // A' prefetch for agg iters 0..3 (independent of Tt -> overlaps barrier)
    short8 apre[4][7];
#pragma unroll
    for (int pf = 0; pf < 4; ++pf)
#pragma unroll
        for (int dt = 0; dt < 7; ++dt)
            apre[pf][dt] = *(const short8*)&Ag[(size_t)nrow[dt] * APITCH + pf * 32 + quad * 8];
    __syncthreads();

    // ======== Agg K-loop over s: accH += Trel(LDS) x A' ========
#pragma unroll
    for (int ki = 0; ki < 7; ++ki) {
        const int k0 = ki * 32 + quad * 8;
        short8 tf[2];
#pragma unroll
        for (int ct = 0; ct < 2; ++ct)
            tf[ct] = *(const short8*)&Tt[((ns * 2 + ct) * 16 + l15) * TTP + k0];
        short8 afr[7];
#pragma unroll
        for (int dt = 0; dt < 7; ++dt)
            afr[dt] = (ki < 4) ? apre[ki][dt]
                               : *(const short8*)&Ag[(size_t)nrow[dt] * APITCH + k0];
#pragma unroll
        for (int ct = 0; ct < 2; ++ct)
#pragma unroll
            for (int dt = 0; dt < 7; ++dt)
                accH[ct][dt] = __builtin_amdgcn_mfma_f32_16x16x32_bf16(tf[ct], afr[dt], accH[ct][dt], 0, 0, 0);
    }

    // Epilogue: lane holds (c = quad*4+r, d = l15); relu + brel, pool, H store
    const float* brel = branch ? brel_fc : brel_sc;
    unsigned short* Hb = Hout + (size_t)branch * NT_T * HDIM;

#pragma unroll
    for (int ct = 0; ct < 2; ++ct) {
        const int c0 = (ns * 2 + ct) * 16 + quad * 4;      // local ch 0..63
        float bb[4], part[4];
#pragma unroll
        for (int r = 0; r < 4; ++r) { bb[r] = brel[half * 64 + c0 + r]; part[r] = 0.0f; }
#pragma unroll
        for (int dt = 0; dt < 7; ++dt) {
            const int d = (ms * 7 + dt) * 16 + l15;
            if (d < NPG) {
                size_t node = (size_t)g * NPG + d;
                ushort4 o;
                unsigned short* po = (unsigned short*)&o;
#pragma unroll
                for (int r = 0; r < 4; ++r) {
                    float v = fmaxf(accH[ct][dt][r] + bb[r], 0.0f);
                    part[r] += v;
                    po[r] = f2bf(v);
                }
                if (IS_L1) *(ushort4*)&Hb[node * HDIM + half * 64 + c0] = o;  // L2: pool only
            }
        }
#pragma unroll
        for (int r = 0; r < 4; ++r) {
            float v = part[r];
            v += __shfl_xor(v, 1);
            v += __shfl_xor(v, 2);
            v += __shfl_xor(v, 4);
            v += __shfl_xor(v, 8);
            if (l15 == 0) atomicAdd(&zsum[c0 + r], v);
        }
    }
    __syncthreads();

    if (tid < 64)
        z[(size_t)g * 512 + branch * 256 + zlayer + half * 64 + tid] =
            zsum[tid] * (branch ? 1.0f : (1.0f / 200.0f));

    if constexpr (!IS_L1) {
        // ---- last block of this graph's 4 runs the MLP head ----
        __shared__ int lastFlag;
        __threadfence();                         // publish z stores device-wide
        __syncthreads();                         // all lanes fenced
        if (tid == 0) lastFlag = (atomicAdd(&gcnt[g], 1) == 3) ? 1 : 0;
        __syncthreads();
        if (lastFlag) {
            __threadfence();                     // acquire remote z writes
            __shared__ float zs[512];
            __shared__ float l1s[128];
            __shared__ float l2s[64];
            __shared__ float logits[2];
            zs[tid]       = z[(size_t)g * 512 + tid];
            zs[tid + 256] = z[(size_t)g * 512 + tid + 256];
            __syncthreads();
            if (tid < 128) {
                float s = b1[tid];
#pragma unroll 8
                for (int k = 0; k < 512; ++k) s = fmaf(zs[k], w1[k * 128 + tid], s);
                l1s[tid] = fmaxf(s, 0.0f);
            }
            __syncthreads();
            if (tid < 64) {
                float s2 = b2[tid];
#pragma unroll 8
                for (int k = 0; k < 128; ++k) s2 = fmaf(l1s[k], w2[k * 64 + tid], s2);
                l2s[tid] = fmaxf(s2, 0.0f);
            }
            __syncthreads();
            if (tid < 2) {
                float s3 = b3[tid];
                for (int k = 0; k < 64; ++k) s3 = fmaf(l2s[k], w3[k * 2 + tid], s3);
                logits[tid] = s3;
            }
            __syncthreads();
            if (tid < 2) {
                float m = fmaxf(logits[0], logits[1]);
                float lse = m + logf(expf(logits[0] - m) + expf(logits[1] - m));
                out[(size_t)g * 2 + tid] = logits[tid] - lse;
            }
        }
    }
}

// ---------------------------------------------------------------------------
extern "C" void kernel_launch(void* const* d_in, const int* in_sizes, int n_in,
                              void* d_out, int out_size, void* d_ws, size_t ws_size,
                              hipStream_t stream) {
    const float* sc_x = (const float*)d_in[0];
    const float* fc_x = (const float*)d_in[1];
    const int* sc_ei  = (const int*)d_in[2];
    const int* fc_ei  = (const int*)d_in[3];
    const float* sc1_wrel = (const float*)d_in[5];
    const float* sc1_brel = (const float*)d_in[6];
    const float* sc1_wroot = (const float*)d_in[7];
    const float* sc2_wrel = (const float*)d_in[8];
    const float* sc2_brel = (const float*)d_in[9];
    const float* sc2_wroot = (const float*)d_in[10];
    const float* fc1_wrel = (const float*)d_in[11];
    const float* fc1_brel = (const float*)d_in[12];
    const float* fc1_wroot = (const float*)d_in[13];
    const float* fc2_wrel = (const float*)d_in[14];
    const float* fc2_brel = (const float*)d_in[15];
    const float* fc2_wroot = (const float*)d_in[16];
    const float* lin1_w = (const float*)d_in[17];
    const float* lin1_b = (const float*)d_in[18];
    const float* lin2_w = (const float*)d_in[19];
    const float* lin2_b = (const float*)d_in[20];
    const float* lin3_w = (const float*)d_in[21];
    const float* lin3_b = (const float*)d_in[22];

    // Workspace (shorts unless noted): Xb | A' | h | W | z | gcnt  (~119 MB)
    unsigned short* Xb = (unsigned short*)d_ws;                 // 2*51200*224
    unsigned short* Ab = Xb + (size_t)2 * NT_T * XPAD;          // 2*256*200*224
    unsigned short* h  = Ab + (size_t)2 * NG * NPG * APITCH;    // 2*51200*128
    unsigned short* Wb = h + (size_t)2 * NT_T * HDIM;           // 2*(W1SZ+W2SZ)
    float* z = (float*)(Wb + (size_t)2 * (W1SZ + W2SZ));        // 256*512 fp32
    int* gcnt = (int*)(z + (size_t)NG * 512);                   // 256 ints

    prep_kernel<<<NB_PREP, 256, 0, stream>>>(
        sc_ei, fc_ei, sc_x, fc_x,
        sc1_wrel, sc1_wroot, fc1_wrel, fc1_wroot,
        sc2_wrel, sc2_wroot, fc2_wrel, fc2_wroot,
        Ab, Xb, Wb, gcnt);

    layer_kernel<true><<<dim3(2, NG, 2), 256, 0, stream>>>(
        Xb, h, Wb, Ab, sc1_brel, fc1_brel, h, z, 0, gcnt,
        lin1_w, lin1_b, lin2_w, lin2_b, lin3_w, lin3_b, (float*)d_out);
    layer_kernel<false><<<dim3(2, NG, 2), 256, 0, stream>>>(
        Xb, h, Wb, Ab, sc2_brel, fc2_brel, h, z, 128, gcnt,
        lin1_w, lin1_b, lin2_w, lin2_b, lin3_w, lin3_b, (float*)d_out);
}

// Round 10
// 281.322 us; speedup vs baseline: 1.4315x; 1.4315x over previous
//
#include <hip/hip_runtime.h>
#include <math.h>

#define NPG   200                 // nodes per graph
#define HDIM  128
#define NG    256
#define NT_T  (NG * NPG)          // 51200
#define EPG_  3200
#define E_T   (NG * EPG_)         // 819200
#define KP1   224                 // layer-1 K (200) padded to mult of 32
#define APITCH 224                // A' row pitch (zero cols >= 200)
#define XPAD  224                 // converted-X row pitch (zero cols >= 200)
#define TTP   232                 // Tt LDS pitch (shorts): 464B, 16B-aligned rows
#define W1SZ  (256 * KP1)
#define W2SZ  (256 * HDIM)

// prep-kernel grid partition
#define NB_ADJ (2 * NG)                       // 512
#define NB_CX  (2 * NT_T * 28 / 256)          // 11200
#define NB_CW  ((2 * (W1SZ + W2SZ)) / 256)    // 704
#define NB_PREP (NB_ADJ + NB_CX + NB_CW)

typedef short short8 __attribute__((ext_vector_type(8)));
typedef float f32x4  __attribute__((ext_vector_type(4)));

__device__ __forceinline__ unsigned short f2bf(float f) {
    union { float f; unsigned int u; } v; v.f = f;
    unsigned int u = v.u;
    u += 0x7FFFu + ((u >> 16) & 1u);       // RNE
    return (unsigned short)(u >> 16);
}

// ---------------------------------------------------------------------------
// Union prep kernel: [0,512) adjacency build; [512,11712) X convert;
// [11712,12416) W convert.
// ---------------------------------------------------------------------------
__global__ __launch_bounds__(256) void prep_kernel(
        const int* __restrict__ sc_ei, const int* __restrict__ fc_ei,
        const float* __restrict__ sc_x, const float* __restrict__ fc_x,
        const float* __restrict__ s1r, const float* __restrict__ s1o,
        const float* __restrict__ f1r, const float* __restrict__ f1o,
        const float* __restrict__ s2r, const float* __restrict__ s2o,
        const float* __restrict__ f2r, const float* __restrict__ f2o,
        unsigned short* __restrict__ A, unsigned short* __restrict__ xb,
        unsigned short* __restrict__ wb) {
    const int b = blockIdx.x, t = threadIdx.x;

    if (b < NB_ADJ) {
        // ---- adjacency: A' = count/max(deg,1) bf16, [branch][g][dst][src pad 224]
        __shared__ unsigned int cnt[10000];    // 200*200 u8 counters in u32
        __shared__ float invdeg[200];
        const int branch = b >> 8, g = b & 255;
        const int* ei = branch ? fc_ei : sc_ei;

        for (int i = t; i < 10000; i += 256) cnt[i] = 0u;
        __syncthreads();
        const int ebase = g * EPG_;
        for (int i = t; i < EPG_; i += 256) {
            int src = ei[ebase + i];
            int dst = ei[E_T + ebase + i];
            int idx = (dst - g * NPG) * NPG + (src - g * NPG);
            atomicAdd(&cnt[idx >> 2], 1u << ((idx & 3) * 8));
        }
        __syncthreads();
        if (t < NPG) {
            unsigned int s = 0;
            for (int w = 0; w < 50; ++w) {
                unsigned int v = cnt[t * 50 + w];
                s += (v & 0xFFu) + ((v >> 8) & 0xFFu) + ((v >> 16) & 0xFFu) + ((v >> 24) & 0xFFu);
            }
            invdeg[t] = 1.0f / fmaxf((float)s, 1.0f);
        }
        __syncthreads();
        unsigned short* Ag = A + ((size_t)branch * NG + g) * NPG * APITCH;
        for (int q = t; q < NPG * (APITCH / 4); q += 256) {
            int row = q / 56;
            int c4  = (q - row * 56) * 4;
            float inv = invdeg[row];
            ushort4 o;
            unsigned short* po = (unsigned short*)&o;
#pragma unroll
            for (int j = 0; j < 4; ++j) {
                int col = c4 + j;
                float v = 0.0f;
                if (col < NPG) {
                    unsigned int w = cnt[row * 50 + (col >> 2)];
                    v = (float)((w >> ((col & 3) * 8)) & 0xFFu) * inv;
                }
                po[j] = f2bf(v);
            }
            *(ushort4*)&Ag[row * APITCH + c4] = o;
        }
    } else if (b < NB_ADJ + NB_CX) {
        // ---- X fp32 [NT,200] -> bf16 [NT,224]
        int c = (b - NB_ADJ) * 256 + t;
        int branch = c / (NT_T * 28);
        int rem = c - branch * (NT_T * 28);
        int node = rem / 28;
        int koff = (rem - node * 28) * 8;
        const float* x = branch ? fc_x : sc_x;
        uint4 o;
        if (koff < 200) {
            const float* p = x + (size_t)node * 200 + koff;
            float4 a = *(const float4*)p;
            float4 bb = *(const float4*)(p + 4);
            o.x = (unsigned)f2bf(a.x) | ((unsigned)f2bf(a.y) << 16);
            o.y = (unsigned)f2bf(a.z) | ((unsigned)f2bf(a.w) << 16);
            o.z = (unsigned)f2bf(bb.x) | ((unsigned)f2bf(bb.y) << 16);
            o.w = (unsigned)f2bf(bb.z) | ((unsigned)f2bf(bb.w) << 16);
        } else {
            o.x = o.y = o.z = o.w = 0u;
        }
        *(uint4*)&xb[((size_t)branch * NT_T + node) * XPAD + koff] = o;
    } else {
        // ---- weights -> packed W^T bf16 [br0L1|br1L1|br0L2|br1L2], rel|root rows
        int idx = (b - NB_ADJ - NB_CX) * 256 + t;
        float v = 0.0f;
        if (idx < 2 * W1SZ) {
            int branch = idx / W1SZ, rem = idx - branch * W1SZ;
            int c = rem / KP1, k = rem - c * KP1;
            const float* wr = branch ? f1r : s1r;
            const float* wo = branch ? f1o : s1o;
            if (k < 200) v = (c < 128) ? wr[(size_t)k * 128 + c] : wo[(size_t)k * 128 + (c - 128)];
        } else {
            int i2 = idx - 2 * W1SZ;
            int branch = i2 / W2SZ, rem = i2 - branch * W2SZ;
            int c = rem / HDIM, k = rem - c * HDIM;
            const float* wr = branch ? f2r : s2r;
            const float* wo = branch ? f2o : s2o;
            v = (c < 128) ? wr[(size_t)k * 128 + c] : wo[(size_t)k * 128 + (c - 128)];
        }
        wb[idx] = f2bf(v);
    }
}

// ---------------------------------------------------------------------------
// Fused GraphConv layer (round-7 structure, merged X-scan + agg + pool).
// Grid: 1024 linear blocks with XCD-pair swizzle: the two channel-halves of
// the same (graph, branch) pair are placed 8 apart in linear block id, so
// round-robin XCD dispatch puts them on the SAME XCD -> the second half's
// X-slab and A'-slab reads (90 KB each) hit that XCD's 4 MB L2 instead of
// HBM (~200 vs ~900 cyc).
//   lin in [0,1024): half = (lin>>3)&1; p = (lin>>4)*8 + (lin&7)  [0,512)
//   g = p & 255, branch = p >> 8 (in {0,1}).  Bijective.
// ---------------------------------------------------------------------------
template<bool IS_L1>
__global__ __launch_bounds__(256, 2) void layer_kernel(
        const unsigned short* __restrict__ Xb,     // L1 input, pitch 224
        const unsigned short* __restrict__ hin,    // L2 input, pitch 128
        const unsigned short* __restrict__ Wall,
        const unsigned short* __restrict__ Aall,
        const float* __restrict__ brel_sc, const float* __restrict__ brel_fc,
        unsigned short* __restrict__ Hout,
        float* __restrict__ z, int zlayer) {
    __shared__ alignas(16) short Tt[64 * TTP];   // 29,696 B
    __shared__ float zsum[64];

    const int tid = threadIdx.x;
    const int lane = tid & 63, wid = tid >> 6;     // 4 waves
    const int l15 = lane & 15, quad = lane >> 4;

    // XCD-pair swizzle decode (1024 blocks)
    const int lin  = blockIdx.x;
    const int half = (lin >> 3) & 1;               // 0/1: channel half
    const int p    = (lin >> 4) * 8 + (lin & 7);   // pair id 0..511
    const int g = p & 255, branch = p >> 8;

    if (tid < 64) zsum[tid] = 0.0f;

    const int KITER = IS_L1 ? 7 : 4;
    const int XP    = IS_L1 ? XPAD : HDIM;
    const int WP    = IS_L1 ? KP1 : HDIM;
    const unsigned short* X = (IS_L1 ? Xb : hin) + (size_t)branch * NT_T * XP;
    const unsigned short* W = Wall + (IS_L1 ? (size_t)branch * W1SZ
                                            : (size_t)2 * W1SZ + (size_t)branch * W2SZ);
    const unsigned short* Xg = X + (size_t)g * NPG * XP;
    const unsigned short* Ag = Aall + ((size_t)branch * NG + g) * NPG * APITCH;

    const int ms = wid & 1;        // node-tile set
    const int ns = wid >> 1;       // channel-tile set

    int nrow[7];
#pragma unroll
    for (int mt = 0; mt < 7; ++mt) {
        int s = (ms * 7 + mt) * 16 + l15;
        nrow[mt] = (s > NPG - 1) ? (NPG - 1) : s;   // clamp; killed by A'=0 / mask
    }
    int wrel_row[2];
#pragma unroll
    for (int nt = 0; nt < 2; ++nt)
        wrel_row[nt] = half * 64 + (ns * 2 + nt) * 16 + l15;

    f32x4 accT[7][2];   // D[m=s][n=c]
    f32x4 accH[2][7];   // D[m=c][n=d]
#pragma unroll
    for (int mt = 0; mt < 7; ++mt)
#pragma unroll
        for (int nt = 0; nt < 2; ++nt)
#pragma unroll
            for (int r = 0; r < 4; ++r) { accT[mt][nt][r] = 0.0f; accH[nt][mt][r] = 0.0f; }

    // ======== Merged X-scan: transform + root term in one pass ========
#pragma unroll
    for (int ki = 0; ki < KITER; ++ki) {
        const int kb = ki * 32 + quad * 8;
        short8 xf[7];
#pragma unroll
        for (int mt = 0; mt < 7; ++mt)
            xf[mt] = *(const short8*)&Xg[nrow[mt] * XP + kb];
        short8 wr[2], wo[2];
#pragma unroll
        for (int nt = 0; nt < 2; ++nt) {
            wr[nt] = *(const short8*)&W[(size_t)wrel_row[nt] * WP + kb];
            wo[nt] = *(const short8*)&W[(size_t)(128 + wrel_row[nt]) * WP + kb];
        }
#pragma unroll
        for (int mt = 0; mt < 7; ++mt)
#pragma unroll
            for (int nt = 0; nt < 2; ++nt)
                accT[mt][nt] = __builtin_amdgcn_mfma_f32_16x16x32_bf16(xf[mt], wr[nt], accT[mt][nt], 0, 0, 0);
#pragma unroll
        for (int nt = 0; nt < 2; ++nt)
#pragma unroll
            for (int mt = 0; mt < 7; ++mt)
                accH[nt][mt] = __builtin_amdgcn_mfma_f32_16x16x32_bf16(wo[nt], xf[mt], accH[nt][mt], 0, 0, 0);
    }

    // accT -> Tt (lane holds s = quad*4+r, c = l15)
#pragma unroll
    for (int mt = 0; mt < 7; ++mt) {
        int s0 = (ms * 7 + mt) * 16 + quad * 4;
#pragma unroll
        for (int nt = 0; nt < 2; ++nt) {
            int c = (ns * 2 + nt) * 16 + l15;
            ushort4 o;
            unsigned short* po = (unsigned short*)&o;
#pragma unroll
            for (int r = 0; r < 4; ++r) po[r] = f2bf(accT[mt][nt][r]);
            *(ushort4*)&Tt[c * TTP + s0] = o;
        }
    }
    __syncthreads();

    // ======== Agg K-loop over s: accH += Trel(LDS) x A'(global) ========
#pragma unroll
    for (int ki = 0; ki < 7; ++ki) {
        const int k0 = ki * 32 + quad * 8;
        short8 tf[2];
#pragma unroll
        for (int ct = 0; ct < 2; ++ct)
            tf[ct] = *(const short8*)&Tt[((ns * 2 + ct) * 16 + l15) * TTP + k0];
        short8 afr[7];
#pragma unroll
        for (int dt = 0; dt < 7; ++dt)
            afr[dt] = *(const short8*)&Ag[(size_t)nrow[dt] * APITCH + k0];
#pragma unroll
        for (int ct = 0; ct < 2; ++ct)
#pragma unroll
            for (int dt = 0; dt < 7; ++dt)
                accH[ct][dt] = __builtin_amdgcn_mfma_f32_16x16x32_bf16(tf[ct], afr[dt], accH[ct][dt], 0, 0, 0);
    }

    // Epilogue: lane holds (c = quad*4+r, d = l15); relu + brel, pool, H store
    const float* brel = branch ? brel_fc : brel_sc;
    unsigned short* Hb = Hout + (size_t)branch * NT_T * HDIM;

#pragma unroll
    for (int ct = 0; ct < 2; ++ct) {
        const int c0 = (ns * 2 + ct) * 16 + quad * 4;      // local ch 0..63
        float bb[4], part[4];
#pragma unroll
        for (int r = 0; r < 4; ++r) { bb[r] = brel[half * 64 + c0 + r]; part[r] = 0.0f; }
#pragma unroll
        for (int dt = 0; dt < 7; ++dt) {
            const int d = (ms * 7 + dt) * 16 + l15;
            if (d < NPG) {
                size_t node = (size_t)g * NPG + d;
                ushort4 o;
                unsigned short* po = (unsigned short*)&o;
#pragma unroll
                for (int r = 0; r < 4; ++r) {
                    float v = fmaxf(accH[ct][dt][r] + bb[r], 0.0f);
                    part[r] += v;
                    po[r] = f2bf(v);
                }
                if (IS_L1) *(ushort4*)&Hb[node * HDIM + half * 64 + c0] = o;  // L2: pool only
            }
        }
        // butterfly over the 16 l15 lanes (d-dim), then 1 LDS atomic per channel
#pragma unroll
        for (int r = 0; r < 4; ++r) {
            float v = part[r];
            v += __shfl_xor(v, 1);
            v += __shfl_xor(v, 2);
            v += __shfl_xor(v, 4);
            v += __shfl_xor(v, 8);
            if (l15 == 0) atomicAdd(&zsum[c0 + r], v);
        }
    }
    __syncthreads();

    if (tid < 64)
        z[(size_t)g * 512 + branch * 256 + zlayer + half * 64 + tid] =
            zsum[tid] * (branch ? 1.0f : (1.0f / 200.0f));
}

// ---------------------------------------------------------------------------
// MLP head (fp32): z[512] -> relu(lin1)[128] -> relu(lin2)[64] -> lin3[2]
// -> log_softmax. One block per graph.
// ---------------------------------------------------------------------------
__global__ __launch_bounds__(128) void mlp_kernel(const float* __restrict__ z,
                                                  const float* __restrict__ w1, const float* __restrict__ b1,
                                                  const float* __restrict__ w2, const float* __restrict__ b2,
                                                  const float* __restrict__ w3, const float* __restrict__ b3,
                                                  float* __restrict__ out) {
    __shared__ float zs[512];
    __shared__ float l1[128];
    __shared__ float l2[64];
    __shared__ float logits[2];
    int g = blockIdx.x, t = threadIdx.x;

#pragma unroll
    for (int i = 0; i < 4; ++i) zs[t + 128 * i] = z[(size_t)g * 512 + t + 128 * i];
    __syncthreads();

    float s = b1[t];
#pragma unroll 8
    for (int k = 0; k < 512; ++k) s = fmaf(zs[k], w1[k * 128 + t], s);
    l1[t] = fmaxf(s, 0.0f);
    __syncthreads();

    if (t < 64) {
        float s2 = b2[t];
#pragma unroll 8
        for (int k = 0; k < 128; ++k) s2 = fmaf(l1[k], w2[k * 64 + t], s2);
        l2[t] = fmaxf(s2, 0.0f);
    }
    __syncthreads();

    if (t < 2) {
        float s3 = b3[t];
        for (int k = 0; k < 64; ++k) s3 = fmaf(l2[k], w3[k * 2 + t], s3);
        logits[t] = s3;
    }
    __syncthreads();

    if (t < 2) {
        float m = fmaxf(logits[0], logits[1]);
        float lse = m + logf(expf(logits[0] - m) + expf(logits[1] - m));
        out[(size_t)g * 2 + t] = logits[t] - lse;
    }
}

// ---------------------------------------------------------------------------
extern "C" void kernel_launch(void* const* d_in, const int* in_sizes, int n_in,
                              void* d_out, int out_size, void* d_ws, size_t ws_size,
                              hipStream_t stream) {
    const float* sc_x = (const float*)d_in[0];
    const float* fc_x = (const float*)d_in[1];
    const int* sc_ei  = (const int*)d_in[2];
    const int* fc_ei  = (const int*)d_in[3];
    const float* sc1_wrel = (const float*)d_in[5];
    const float* sc1_brel = (const float*)d_in[6];
    const float* sc1_wroot = (const float*)d_in[7];
    const float* sc2_wrel = (const float*)d_in[8];
    const float* sc2_brel = (const float*)d_in[9];
    const float* sc2_wroot = (const float*)d_in[10];
    const float* fc1_wrel = (const float*)d_in[11];
    const float* fc1_brel = (const float*)d_in[12];
    const float* fc1_wroot = (const float*)d_in[13];
    const float* fc2_wrel = (const float*)d_in[14];
    const float* fc2_brel = (const float*)d_in[15];
    const float* fc2_wroot = (const float*)d_in[16];
    const float* lin1_w = (const float*)d_in[17];
    const float* lin1_b = (const float*)d_in[18];
    const float* lin2_w = (const float*)d_in[19];
    const float* lin2_b = (const float*)d_in[20];
    const float* lin3_w = (const float*)d_in[21];
    const float* lin3_b = (const float*)d_in[22];

    // Workspace (shorts unless noted): Xb | A' | h | W | z  (~119 MB)
    unsigned short* Xb = (unsigned short*)d_ws;                 // 2*51200*224
    unsigned short* Ab = Xb + (size_t)2 * NT_T * XPAD;          // 2*256*200*224
    unsigned short* h  = Ab + (size_t)2 * NG * NPG * APITCH;    // 2*51200*128
    unsigned short* Wb = h + (size_t)2 * NT_T * HDIM;           // 2*(W1SZ+W2SZ)
    float* z = (float*)(Wb + (size_t)2 * (W1SZ + W2SZ));        // 256*512 fp32

    prep_kernel<<<NB_PREP, 256, 0, stream>>>(
        sc_ei, fc_ei, sc_x, fc_x,
        sc1_wrel, sc1_wroot, fc1_wrel, fc1_wroot,
        sc2_wrel, sc2_wroot, fc2_wrel, fc2_wroot,
        Ab, Xb, Wb);

    layer_kernel<true><<<1024, 256, 0, stream>>>(
        Xb, h, Wb, Ab, sc1_brel, fc1_brel, h, z, 0);
    layer_kernel<false><<<1024, 256, 0, stream>>>(
        Xb, h, Wb, Ab, sc2_brel, fc2_brel, h, z, 128);

    mlp_kernel<<<NG, 128, 0, stream>>>(z, lin1_w, lin1_b, lin2_w, lin2_b,
                                       lin3_w, lin3_b, (float*)d_out);
}